// Round 1
// baseline (311.153 us; speedup 1.0000x reference)
//
#include <hip/hip_runtime.h>

// MQA forward. All reference dtypes float32. Compute in bf16 MFMA, fp32 accum.
// HIDDEN=2048, HEADS=16, HEAD_DIM=128, M=4096 tokens (b=2, s=2048).
// Round 9: attention PV consumes P directly from registers. The S^T C-layout
// (row = quad*4 + reg) of the 16x16x32 QK^T MFMA matches the B-operand
// k-layout (k = quad*4 + elem) of mfma_f32_16x16x16_bf16 exactly, so the
// P^T LDS round-trip (8 ds_write_b64 + lgkmcnt(0) drain + 4 ds_read_b128 per
// wave per tile) is deleted. Ps LDS (18KB) freed; V frags become b64 reads.
// GEMM/cvt kernels unchanged from round 8 for attribution.

using bf16   = __bf16;
using bf16x4 = __bf16 __attribute__((ext_vector_type(4)));
using bf16x8 = __bf16 __attribute__((ext_vector_type(8)));
using f32x4  = float  __attribute__((ext_vector_type(4)));
using s4     = short  __attribute__((ext_vector_type(4)));

#define GAS __attribute__((address_space(1)))
#define LAS __attribute__((address_space(3)))

// Async global->LDS, 16B per lane. LDS dest is wave-uniform base + lane*16.
__device__ __forceinline__ void load_lds16(const bf16* g, bf16* l) {
    __builtin_amdgcn_global_load_lds((const GAS void*)g, (LAS void*)l, 16, 0, 0);
}

// PV MFMA: D = A(16x16) * B(16x16) + C, bf16 inputs, K=16.
// B-frag: col = lane&15, k = quad*4 + elem  == S^T C-layout from QK^T.
__device__ __forceinline__ f32x4 mfma_pv(s4 a, s4 b, f32x4 c) {
#if __has_builtin(__builtin_amdgcn_mfma_f32_16x16x16bf16_1k)
    return __builtin_amdgcn_mfma_f32_16x16x16bf16_1k(a, b, c, 0, 0, 0);
#else
    asm("v_mfma_f32_16x16x16_bf16 %0, %1, %2, %0" : "+v"(c) : "v"(a), "v"(b));
    return c;
#endif
}

// 1/sqrt(128) * log2(e): folds attention scale AND exp->exp2 conversion into Q.
#define Q_SCALE_LOG2 0.12751745f

// ---------------------------------------------------------------------------
// Fused f32 -> bf16 conversion of all 5 inputs into contiguous bf16 scratch.
// ---------------------------------------------------------------------------
__global__ __launch_bounds__(256) void cvt_all(
    const float* __restrict__ x,  const float* __restrict__ wq,
    const float* __restrict__ wk, const float* __restrict__ wv,
    const float* __restrict__ wo, bf16* __restrict__ dst)
{
    const size_t i = (size_t)(blockIdx.x * 256 + threadIdx.x) * 8;
    const float* src; size_t off;
    if      (i <  8388608) { src = x;  off = 0; }
    else if (i < 12582912) { src = wq; off = 8388608; }
    else if (i < 12845056) { src = wk; off = 12582912; }
    else if (i < 13107200) { src = wv; off = 12845056; }
    else                   { src = wo; off = 13107200; }
    float4 f0 = *(const float4*)(src + (i - off));
    float4 f1 = *(const float4*)(src + (i - off) + 4);
    bf16x8 v;
    v[0] = (bf16)f0.x; v[1] = (bf16)f0.y; v[2] = (bf16)f0.z; v[3] = (bf16)f0.w;
    v[4] = (bf16)f1.x; v[5] = (bf16)f1.y; v[6] = (bf16)f1.z; v[7] = (bf16)f1.w;
    *(bf16x8*)(dst + i) = v;
}

// ---------------------------------------------------------------------------
// 128x128-tile NT GEMM core: C[M][N] = scale * A[M][2048] * B[N][2048]^T.
// m97 structure: BK=32, global_load_lds width-16 staging, 16 MFMA / K-step.
// mode: 0 = bf16 C (scaled), 1 = bf16 C transposed (C[n][m]), 2 = f32 C.
// ---------------------------------------------------------------------------
__device__ __forceinline__ void gemm128(
    const bf16* __restrict__ A, const bf16* __restrict__ B, void* __restrict__ Cp,
    int bm, int bn, int ldC, int mode, float scale)
{
    __shared__ bf16 As[128 * 32];
    __shared__ bf16 Bs[128 * 32];
    const int K = 2048;

    const int tid  = threadIdx.x;
    const int wave = tid >> 6;
    const int lane = tid & 63;
    const int quad = lane >> 4;
    const int c    = lane & 15;
    const int wm   = (wave >> 1) << 6;
    const int wn   = (wave & 1) << 6;

    const int srow = tid >> 2;
    const int scol = (tid & 3) << 3;
    const bf16* Ag = A + (size_t)(bm + srow) * K + scol;
    const bf16* Bg = B + (size_t)(bn + srow) * K + scol;
    bf16* lA = As + wave * 512;
    bf16* lB = Bs + wave * 512;

    f32x4 acc[4][4];
#pragma unroll
    for (int i = 0; i < 4; ++i)
#pragma unroll
        for (int j = 0; j < 4; ++j)
            acc[i][j] = f32x4{0.f, 0.f, 0.f, 0.f};

    for (int k0 = 0; k0 < K; k0 += 32) {
        load_lds16(Ag + k0,          lA);
        load_lds16(Ag + k0 + 64 * K, lA + 2048);
        load_lds16(Bg + k0,          lB);
        load_lds16(Bg + k0 + 64 * K, lB + 2048);
        __syncthreads();

        bf16x8 af[4], bfv[4];
#pragma unroll
        for (int i = 0; i < 4; ++i)
            af[i] = *(const bf16x8*)(As + (wm + i * 16 + c) * 32 + quad * 8);
#pragma unroll
        for (int j = 0; j < 4; ++j)
            bfv[j] = *(const bf16x8*)(Bs + (wn + j * 16 + c) * 32 + quad * 8);
#pragma unroll
        for (int i = 0; i < 4; ++i)
#pragma unroll
            for (int j = 0; j < 4; ++j)
                acc[i][j] = __builtin_amdgcn_mfma_f32_16x16x32_bf16(af[i], bfv[j], acc[i][j], 0, 0, 0);
        __syncthreads();
    }

    // C/D layout: col = lane&15, row = quad*4 + reg
    if (mode == 0) {
        bf16* C = (bf16*)Cp;
#pragma unroll
        for (int i = 0; i < 4; ++i) {
            const int m = bm + wm + i * 16 + quad * 4;
#pragma unroll
            for (int j = 0; j < 4; ++j) {
                const int n = bn + wn + j * 16 + c;
#pragma unroll
                for (int r = 0; r < 4; ++r)
                    C[(size_t)(m + r) * ldC + n] = (bf16)(acc[i][j][r] * scale);
            }
        }
    } else if (mode == 1) {
        bf16* C = (bf16*)Cp;
#pragma unroll
        for (int j = 0; j < 4; ++j) {
            const int n = bn + wn + j * 16 + c;
#pragma unroll
            for (int i = 0; i < 4; ++i) {
                const int m = bm + wm + i * 16 + quad * 4;
                bf16x4 v;
#pragma unroll
                for (int r = 0; r < 4; ++r) v[r] = (bf16)acc[i][j][r];
                *(bf16x4*)(C + (size_t)n * ldC + m) = v;
            }
        }
    } else {
        float* C = (float*)Cp;
#pragma unroll
        for (int i = 0; i < 4; ++i) {
            const int m = bm + wm + i * 16 + quad * 4;
#pragma unroll
            for (int j = 0; j < 4; ++j) {
                const int n = bn + wn + j * 16 + c;
#pragma unroll
                for (int r = 0; r < 4; ++r)
                    C[(size_t)(m + r) * ldC + n] = acc[i][j][r];
            }
        }
    }
}

// bx 0..15: Q = (x @ w_q^T) * Q_SCALE_LOG2; bx==16: K = x @ w_k^T; bx==17: V^T
__global__ __launch_bounds__(256, 3) void qkv_kernel(
    const bf16* __restrict__ x,  const bf16* __restrict__ wq,
    const bf16* __restrict__ wk, const bf16* __restrict__ wv,
    bf16* __restrict__ Qb, bf16* __restrict__ Kb, bf16* __restrict__ Vt)
{
    const int bx = blockIdx.x;
    const int bm = blockIdx.y << 7;
    const bf16* B; bf16* C; int ldC, bn, mode; float sc;
    if (bx < 16)       { B = wq; C = Qb; ldC = 2048; bn = bx << 7; mode = 0; sc = Q_SCALE_LOG2; }
    else if (bx == 16) { B = wk; C = Kb; ldC = 128;  bn = 0;       mode = 0; sc = 1.0f; }
    else               { B = wv; C = Vt; ldC = 4096; bn = 0;       mode = 1; sc = 1.0f; }
    gemm128(x, B, C, bm, bn, ldC, mode, sc);
}

__global__ __launch_bounds__(256, 3) void out_kernel(
    const bf16* __restrict__ AO, const bf16* __restrict__ wo, float* __restrict__ out)
{
    gemm128(AO, wo, out, blockIdx.y << 7, blockIdx.x << 7, 2048, 2, 1.0f);
}

// ---------------------------------------------------------------------------
// Flash attention, S^T form, log2-domain no-max softmax.
// Round 9: P^T stays in registers; PV via 16x16x16 MFMAs. No Ps LDS.
// ---------------------------------------------------------------------------
#define KS_LD 136   // 128 + 8 pad
#define VS_LD 72    // 64 + 8 pad

__global__ __launch_bounds__(256, 2) void attn_kernel(
    const bf16* __restrict__ Qb, const bf16* __restrict__ Kb,
    const bf16* __restrict__ Vt, bf16* __restrict__ AO)
{
    __shared__ bf16 Ks[64 * KS_LD];   // [t][d]
    __shared__ bf16 Vs[128 * VS_LD];  // [d][t]

    const int tid  = threadIdx.x;
    const int lane = tid & 63;
    const int wave = tid >> 6;
    const int q    = lane >> 4;       // quad
    const int c    = lane & 15;
    const int qt = blockIdx.x, h = blockIdx.y, b = blockIdx.z;
    const int rowbase = b * 2048 + qt * 128;
    const int wrow = wave * 32;

    // Q (pre-scaled) as B-operand frags: Q[qrow=wrow+nq*16+c][d=ks*32+q*8 ..+7]
    bf16x8 qf[2][4];
#pragma unroll
    for (int nq = 0; nq < 2; ++nq)
#pragma unroll
        for (int ks = 0; ks < 4; ++ks)
            qf[nq][ks] = *(const bf16x8*)(Qb + (size_t)(rowbase + wrow + nq * 16 + c) * 2048
                                             + h * 128 + ks * 32 + q * 8);

    f32x4 o[8][2];   // O^T accum: lane holds d = mtv*16+q*4+r, qrow = nq*16+c
#pragma unroll
    for (int mtv = 0; mtv < 8; ++mtv)
#pragma unroll
        for (int nq = 0; nq < 2; ++nq) o[mtv][nq] = f32x4{0.f, 0.f, 0.f, 0.f};

    float psum[2] = {0.f, 0.f};   // per-lane partial row-sums, reduced at end

    const int krow = tid >> 4, kcol = (tid & 15) << 3;
    const int vrow = tid >> 3, vcol = (tid & 7) << 3;
    const bf16* Kg = Kb + (size_t)b * 2048 * 128;
    const bf16* Vg = Vt + (size_t)b * 2048;

    for (int t0 = 0; t0 < 2048; t0 += 64) {
        // prefetch K/V tile into registers (overlaps with previous tile's math)
        bf16x8 kreg[4], vreg[4];
#pragma unroll
        for (int p = 0; p < 4; ++p)
            kreg[p] = *(const bf16x8*)(Kg + (size_t)(t0 + p * 16 + krow) * 128 + kcol);
#pragma unroll
        for (int p = 0; p < 4; ++p)
            vreg[p] = *(const bf16x8*)(Vg + (size_t)(p * 32 + vrow) * 4096 + t0 + vcol);

        __syncthreads();   // barrier 1: prev tile's frag reads done
#pragma unroll
        for (int p = 0; p < 4; ++p)
            *(bf16x8*)(Ks + (p * 16 + krow) * KS_LD + kcol) = kreg[p];
#pragma unroll
        for (int p = 0; p < 4; ++p)
            *(bf16x8*)(Vs + (p * 32 + vrow) * VS_LD + vcol) = vreg[p];
        __syncthreads();   // barrier 2: staging visible

        // ---- S^T = K Qs^T : lane holds S^T[mt*16+q*4+r][nq*16+c], log2 domain ----
        f32x4 s[4][2];
#pragma unroll
        for (int mt = 0; mt < 4; ++mt)
#pragma unroll
            for (int nq = 0; nq < 2; ++nq) s[mt][nq] = f32x4{0.f, 0.f, 0.f, 0.f};
#pragma unroll
        for (int ks = 0; ks < 4; ++ks) {
            bf16x8 kf[4];
#pragma unroll
            for (int mt = 0; mt < 4; ++mt)
                kf[mt] = *(const bf16x8*)(Ks + (mt * 16 + c) * KS_LD + ks * 32 + q * 8);
#pragma unroll
            for (int mt = 0; mt < 4; ++mt)
#pragma unroll
                for (int nq = 0; nq < 2; ++nq)
                    s[mt][nq] = __builtin_amdgcn_mfma_f32_16x16x32_bf16(kf[mt], qf[nq][ks], s[mt][nq], 0, 0, 0);
        }

        // ---- per 16-row t-block: p = exp2(s) -> bf16 B-frag in regs, then PV ----
        // S^T C-layout row (= t within block) is quad*4+r, which IS the
        // 16x16x16 B-operand k-index (quad*4+elem): no LDS round-trip.
#pragma unroll
        for (int mt = 0; mt < 4; ++mt) {
            s4 pv[2];
#pragma unroll
            for (int nq = 0; nq < 2; ++nq) {
#pragma unroll
                for (int r = 0; r < 4; ++r) {
                    const float p = exp2f(s[mt][nq][r]);
                    psum[nq] += p;
                    pv[nq][r] = __builtin_bit_cast(short, (bf16)p);
                }
            }
            // V^T A-frags for this t-block: row = mtv*16+c (d), k = q*4..+3 (t)
            s4 vb[8];
#pragma unroll
            for (int mtv = 0; mtv < 8; ++mtv)
                vb[mtv] = *(const s4*)(Vs + (mtv * 16 + c) * VS_LD + mt * 16 + q * 4);
#pragma unroll
            for (int mtv = 0; mtv < 8; ++mtv)
#pragma unroll
                for (int nq = 0; nq < 2; ++nq)
                    o[mtv][nq] = mfma_pv(vb[mtv], pv[nq], o[mtv][nq]);
        }
    }

    // final l per qrow: reduce per-lane partials across quads
#pragma unroll
    for (int nq = 0; nq < 2; ++nq) {
        float v = psum[nq];
        v += __shfl_xor(v, 16);
        v += __shfl_xor(v, 32);
        psum[nq] = v;
    }

    // epilogue: AO[qrow][h*128 + d], packed 8B stores
#pragma unroll
    for (int nq = 0; nq < 2; ++nq) {
        const float rinv = 1.0f / psum[nq];
        const size_t row = (size_t)(rowbase + wrow + nq * 16 + c) * 2048 + h * 128;
#pragma unroll
        for (int mtv = 0; mtv < 8; ++mtv) {
            bf16x4 v;
#pragma unroll
            for (int r = 0; r < 4; ++r) v[r] = (bf16)(o[mtv][nq][r] * rinv);
            *(bf16x4*)(AO + row + mtv * 16 + q * 4) = v;
        }
    }
}

// ---------------------------------------------------------------------------
extern "C" void kernel_launch(void* const* d_in, const int* in_sizes, int n_in,
                              void* d_out, int out_size, void* d_ws, size_t ws_size,
                              hipStream_t stream)
{
    const float* x  = (const float*)d_in[0];
    const float* wq = (const float*)d_in[1];
    const float* wk = (const float*)d_in[2];
    const float* wv = (const float*)d_in[3];
    const float* wo = (const float*)d_in[4];
    float* out = (float*)d_out;

    // workspace (bf16), 51 MiB total:
    // xb@0(16M) wqb@16M(8M) wkb@24M(.5M) wvb@24.5M(.5M) wob@25M(8M) Qb/AO@33M(16M) Kb@49M(1M) Vt@50M(1M)
    char* ws = (char*)d_ws;
    const size_t MB = 1024 * 1024;
    bf16* xb  = (bf16*)(ws);
    bf16* wqb = (bf16*)(ws + 16 * MB);
    bf16* wkb = (bf16*)(ws + 24 * MB);
    bf16* wvb = (bf16*)(ws + 24 * MB + 512 * 1024);
    bf16* wob = (bf16*)(ws + 25 * MB);
    bf16* Qb  = (bf16*)(ws + 33 * MB);
    bf16* AO  = Qb;                            // alias (safe, see attn note)
    bf16* Kb  = (bf16*)(ws + 49 * MB);
    bf16* Vt  = (bf16*)(ws + 50 * MB);

    cvt_all<<<17301504 / 2048, 256, 0, stream>>>(x, wq, wk, wv, wo, xb);
    qkv_kernel<<<dim3(18, 32), 256, 0, stream>>>(xb, wqb, wkb, wvb, Qb, Kb, Vt);
    attn_kernel<<<dim3(16, 16, 2), 256, 0, stream>>>(Qb, Kb, Vt, AO);
    out_kernel<<<dim3(16, 32), 256, 0, stream>>>(AO, wob, out);
}

// Round 2
// 292.643 us; speedup vs baseline: 1.0633x; 1.0633x over previous
//
#include <hip/hip_runtime.h>

// MQA forward. All reference dtypes float32. Compute in bf16 MFMA, fp32 accum.
// HIDDEN=2048, HEADS=16, HEAD_DIM=128, M=4096 tokens (b=2, s=2048).
// Round 10: register-direct PV at FULL K=32 MFMA rate. Round 9 showed
// 16x16x16 MFMA issues at the same cycles as 16x16x32 (half rate) -> PV pipe
// time doubled. Fix: rebuild K=32 B-fragments from the S^T accumulator via
// gfx950's two-register lane swaps:
//   perm32_swap(A,B): A=[A_lo|B_lo], B=[A_hi|B_hi]   (quad {0,1}<->{2,3})
//   perm16_swap(X,Y): X=[Xq0|Yq0|Xq2|Yq2], Y=[Xq1|Yq1|Xq3|Yq3]
// Target B-frag word w at lane (c,quad) needs k = quad*8 + 2w,2w+1 over a
// 32-row t-block = two 16-row S^T blocks; the swap pair produces exactly
// (w0,w2) from (pack(r0,r1) of both blocks) and (w1,w3) from pack(r2,r3).
// Ps LDS, its 4-way-conflicted writes, and the per-tile lgkmcnt drain stay
// deleted (round 9's win); PV MFMA count returns to round 8's 32x K=32.
// GEMM/cvt kernels unchanged.

using bf16   = __bf16;
using bf16x2 = __bf16 __attribute__((ext_vector_type(2)));
using bf16x4 = __bf16 __attribute__((ext_vector_type(4)));
using bf16x8 = __bf16 __attribute__((ext_vector_type(8)));
using f32x4  = float  __attribute__((ext_vector_type(4)));
using u32x4  = unsigned __attribute__((ext_vector_type(4)));

#define GAS __attribute__((address_space(1)))
#define LAS __attribute__((address_space(3)))

// Async global->LDS, 16B per lane. LDS dest is wave-uniform base + lane*16.
__device__ __forceinline__ void load_lds16(const bf16* g, bf16* l) {
    __builtin_amdgcn_global_load_lds((const GAS void*)g, (LAS void*)l, 16, 0, 0);
}

// Pack two f32 -> one u32 of 2 bf16 (compiler fuses to v_cvt_pk_bf16_f32).
__device__ __forceinline__ unsigned pkbf(float a, float b) {
    bf16x2 t; t[0] = (bf16)a; t[1] = (bf16)b;
    return __builtin_bit_cast(unsigned, t);
}
// a_hi <-> b_lo (32-lane halves)
__device__ __forceinline__ void perm32(unsigned& a, unsigned& b) {
    asm volatile("v_permlane32_swap_b32 %0, %1" : "+v"(a), "+v"(b));
}
// a's odd 16-groups <-> b's even 16-groups
__device__ __forceinline__ void perm16(unsigned& a, unsigned& b) {
    asm volatile("v_permlane16_swap_b32 %0, %1" : "+v"(a), "+v"(b));
}

// 1/sqrt(128) * log2(e): folds attention scale AND exp->exp2 conversion into Q.
#define Q_SCALE_LOG2 0.12751745f

// ---------------------------------------------------------------------------
// Fused f32 -> bf16 conversion of all 5 inputs into contiguous bf16 scratch.
// ---------------------------------------------------------------------------
__global__ __launch_bounds__(256) void cvt_all(
    const float* __restrict__ x,  const float* __restrict__ wq,
    const float* __restrict__ wk, const float* __restrict__ wv,
    const float* __restrict__ wo, bf16* __restrict__ dst)
{
    const size_t i = (size_t)(blockIdx.x * 256 + threadIdx.x) * 8;
    const float* src; size_t off;
    if      (i <  8388608) { src = x;  off = 0; }
    else if (i < 12582912) { src = wq; off = 8388608; }
    else if (i < 12845056) { src = wk; off = 12582912; }
    else if (i < 13107200) { src = wv; off = 12845056; }
    else                   { src = wo; off = 13107200; }
    float4 f0 = *(const float4*)(src + (i - off));
    float4 f1 = *(const float4*)(src + (i - off) + 4);
    bf16x8 v;
    v[0] = (bf16)f0.x; v[1] = (bf16)f0.y; v[2] = (bf16)f0.z; v[3] = (bf16)f0.w;
    v[4] = (bf16)f1.x; v[5] = (bf16)f1.y; v[6] = (bf16)f1.z; v[7] = (bf16)f1.w;
    *(bf16x8*)(dst + i) = v;
}

// ---------------------------------------------------------------------------
// 128x128-tile NT GEMM core: C[M][N] = scale * A[M][2048] * B[N][2048]^T.
// m97 structure: BK=32, global_load_lds width-16 staging, 16 MFMA / K-step.
// mode: 0 = bf16 C (scaled), 1 = bf16 C transposed (C[n][m]), 2 = f32 C.
// ---------------------------------------------------------------------------
__device__ __forceinline__ void gemm128(
    const bf16* __restrict__ A, const bf16* __restrict__ B, void* __restrict__ Cp,
    int bm, int bn, int ldC, int mode, float scale)
{
    __shared__ bf16 As[128 * 32];
    __shared__ bf16 Bs[128 * 32];
    const int K = 2048;

    const int tid  = threadIdx.x;
    const int wave = tid >> 6;
    const int lane = tid & 63;
    const int quad = lane >> 4;
    const int c    = lane & 15;
    const int wm   = (wave >> 1) << 6;
    const int wn   = (wave & 1) << 6;

    const int srow = tid >> 2;
    const int scol = (tid & 3) << 3;
    const bf16* Ag = A + (size_t)(bm + srow) * K + scol;
    const bf16* Bg = B + (size_t)(bn + srow) * K + scol;
    bf16* lA = As + wave * 512;
    bf16* lB = Bs + wave * 512;

    f32x4 acc[4][4];
#pragma unroll
    for (int i = 0; i < 4; ++i)
#pragma unroll
        for (int j = 0; j < 4; ++j)
            acc[i][j] = f32x4{0.f, 0.f, 0.f, 0.f};

    for (int k0 = 0; k0 < K; k0 += 32) {
        load_lds16(Ag + k0,          lA);
        load_lds16(Ag + k0 + 64 * K, lA + 2048);
        load_lds16(Bg + k0,          lB);
        load_lds16(Bg + k0 + 64 * K, lB + 2048);
        __syncthreads();

        bf16x8 af[4], bfv[4];
#pragma unroll
        for (int i = 0; i < 4; ++i)
            af[i] = *(const bf16x8*)(As + (wm + i * 16 + c) * 32 + quad * 8);
#pragma unroll
        for (int j = 0; j < 4; ++j)
            bfv[j] = *(const bf16x8*)(Bs + (wn + j * 16 + c) * 32 + quad * 8);
#pragma unroll
        for (int i = 0; i < 4; ++i)
#pragma unroll
            for (int j = 0; j < 4; ++j)
                acc[i][j] = __builtin_amdgcn_mfma_f32_16x16x32_bf16(af[i], bfv[j], acc[i][j], 0, 0, 0);
        __syncthreads();
    }

    // C/D layout: col = lane&15, row = quad*4 + reg
    if (mode == 0) {
        bf16* C = (bf16*)Cp;
#pragma unroll
        for (int i = 0; i < 4; ++i) {
            const int m = bm + wm + i * 16 + quad * 4;
#pragma unroll
            for (int j = 0; j < 4; ++j) {
                const int n = bn + wn + j * 16 + c;
#pragma unroll
                for (int r = 0; r < 4; ++r)
                    C[(size_t)(m + r) * ldC + n] = (bf16)(acc[i][j][r] * scale);
            }
        }
    } else if (mode == 1) {
        bf16* C = (bf16*)Cp;
#pragma unroll
        for (int j = 0; j < 4; ++j) {
            const int n = bn + wn + j * 16 + c;
#pragma unroll
            for (int i = 0; i < 4; ++i) {
                const int m = bm + wm + i * 16 + quad * 4;
                bf16x4 v;
#pragma unroll
                for (int r = 0; r < 4; ++r) v[r] = (bf16)acc[i][j][r];
                *(bf16x4*)(C + (size_t)n * ldC + m) = v;
            }
        }
    } else {
        float* C = (float*)Cp;
#pragma unroll
        for (int i = 0; i < 4; ++i) {
            const int m = bm + wm + i * 16 + quad * 4;
#pragma unroll
            for (int j = 0; j < 4; ++j) {
                const int n = bn + wn + j * 16 + c;
#pragma unroll
                for (int r = 0; r < 4; ++r)
                    C[(size_t)(m + r) * ldC + n] = acc[i][j][r];
            }
        }
    }
}

// bx 0..15: Q = (x @ w_q^T) * Q_SCALE_LOG2; bx==16: K = x @ w_k^T; bx==17: V^T
__global__ __launch_bounds__(256, 3) void qkv_kernel(
    const bf16* __restrict__ x,  const bf16* __restrict__ wq,
    const bf16* __restrict__ wk, const bf16* __restrict__ wv,
    bf16* __restrict__ Qb, bf16* __restrict__ Kb, bf16* __restrict__ Vt)
{
    const int bx = blockIdx.x;
    const int bm = blockIdx.y << 7;
    const bf16* B; bf16* C; int ldC, bn, mode; float sc;
    if (bx < 16)       { B = wq; C = Qb; ldC = 2048; bn = bx << 7; mode = 0; sc = Q_SCALE_LOG2; }
    else if (bx == 16) { B = wk; C = Kb; ldC = 128;  bn = 0;       mode = 0; sc = 1.0f; }
    else               { B = wv; C = Vt; ldC = 4096; bn = 0;       mode = 1; sc = 1.0f; }
    gemm128(x, B, C, bm, bn, ldC, mode, sc);
}

__global__ __launch_bounds__(256, 3) void out_kernel(
    const bf16* __restrict__ AO, const bf16* __restrict__ wo, float* __restrict__ out)
{
    gemm128(AO, wo, out, blockIdx.y << 7, blockIdx.x << 7, 2048, 2, 1.0f);
}

// ---------------------------------------------------------------------------
// Flash attention, S^T form, log2-domain no-max softmax.
// Round 10: P^T in registers, redistributed to K=32 B-frags via permlane swaps.
// ---------------------------------------------------------------------------
#define KS_LD 136   // 128 + 8 pad
#define VS_LD 72    // 64 + 8 pad

__global__ __launch_bounds__(256, 2) void attn_kernel(
    const bf16* __restrict__ Qb, const bf16* __restrict__ Kb,
    const bf16* __restrict__ Vt, bf16* __restrict__ AO)
{
    __shared__ bf16 Ks[64 * KS_LD];   // [t][d]
    __shared__ bf16 Vs[128 * VS_LD];  // [d][t]

    const int tid  = threadIdx.x;
    const int lane = tid & 63;
    const int wave = tid >> 6;
    const int q    = lane >> 4;       // quad
    const int c    = lane & 15;
    const int qt = blockIdx.x, h = blockIdx.y, b = blockIdx.z;
    const int rowbase = b * 2048 + qt * 128;
    const int wrow = wave * 32;

    // Q (pre-scaled) as B-operand frags: Q[qrow=wrow+nq*16+c][d=ks*32+q*8 ..+7]
    bf16x8 qf[2][4];
#pragma unroll
    for (int nq = 0; nq < 2; ++nq)
#pragma unroll
        for (int ks = 0; ks < 4; ++ks)
            qf[nq][ks] = *(const bf16x8*)(Qb + (size_t)(rowbase + wrow + nq * 16 + c) * 2048
                                             + h * 128 + ks * 32 + q * 8);

    f32x4 o[8][2];   // O^T accum: lane holds d = mtv*16+q*4+r, qrow = nq*16+c
#pragma unroll
    for (int mtv = 0; mtv < 8; ++mtv)
#pragma unroll
        for (int nq = 0; nq < 2; ++nq) o[mtv][nq] = f32x4{0.f, 0.f, 0.f, 0.f};

    float psum[2] = {0.f, 0.f};   // per-lane partial row-sums, reduced at end

    const int krow = tid >> 4, kcol = (tid & 15) << 3;
    const int vrow = tid >> 3, vcol = (tid & 7) << 3;
    const bf16* Kg = Kb + (size_t)b * 2048 * 128;
    const bf16* Vg = Vt + (size_t)b * 2048;

    for (int t0 = 0; t0 < 2048; t0 += 64) {
        // prefetch K/V tile into registers (overlaps with previous tile's math)
        bf16x8 kreg[4], vreg[4];
#pragma unroll
        for (int p = 0; p < 4; ++p)
            kreg[p] = *(const bf16x8*)(Kg + (size_t)(t0 + p * 16 + krow) * 128 + kcol);
#pragma unroll
        for (int p = 0; p < 4; ++p)
            vreg[p] = *(const bf16x8*)(Vg + (size_t)(p * 32 + vrow) * 4096 + t0 + vcol);

        __syncthreads();   // barrier 1: prev tile's frag reads done
#pragma unroll
        for (int p = 0; p < 4; ++p)
            *(bf16x8*)(Ks + (p * 16 + krow) * KS_LD + kcol) = kreg[p];
#pragma unroll
        for (int p = 0; p < 4; ++p)
            *(bf16x8*)(Vs + (p * 32 + vrow) * VS_LD + vcol) = vreg[p];
        __syncthreads();   // barrier 2: staging visible

        // ---- S^T = K Qs^T : lane holds S^T[mt*16+q*4+r][nq*16+c], log2 domain ----
        f32x4 s[4][2];
#pragma unroll
        for (int mt = 0; mt < 4; ++mt)
#pragma unroll
            for (int nq = 0; nq < 2; ++nq) s[mt][nq] = f32x4{0.f, 0.f, 0.f, 0.f};
#pragma unroll
        for (int ks = 0; ks < 4; ++ks) {
            bf16x8 kf[4];
#pragma unroll
            for (int mt = 0; mt < 4; ++mt)
                kf[mt] = *(const bf16x8*)(Ks + (mt * 16 + c) * KS_LD + ks * 32 + q * 8);
#pragma unroll
            for (int mt = 0; mt < 4; ++mt)
#pragma unroll
                for (int nq = 0; nq < 2; ++nq)
                    s[mt][nq] = __builtin_amdgcn_mfma_f32_16x16x32_bf16(kf[mt], qf[nq][ks], s[mt][nq], 0, 0, 0);
        }

        // ---- p = exp2(s) in registers, accumulate row-sums ----
        float p[4][2][4];
#pragma unroll
        for (int mt = 0; mt < 4; ++mt)
#pragma unroll
            for (int nq = 0; nq < 2; ++nq)
#pragma unroll
                for (int r = 0; r < 4; ++r) {
                    const float e = exp2f(s[mt][nq][r]);
                    p[mt][nq][r] = e;
                    psum[nq] += e;
                }

        // ---- O^T += V^T P^T, P^T frags built in-register via permlane swaps ----
        // j selects a 32-row t-block = S^T blocks (2j, 2j+1).
#pragma unroll
        for (int j = 0; j < 2; ++j) {
            bf16x8 vb[8];
#pragma unroll
            for (int mtv = 0; mtv < 8; ++mtv)
                vb[mtv] = *(const bf16x8*)(Vs + (mtv * 16 + c) * VS_LD + j * 32 + q * 8);
#pragma unroll
            for (int nq = 0; nq < 2; ++nq) {
                unsigned a0 = pkbf(p[2 * j][nq][0],     p[2 * j][nq][1]);
                unsigned a1 = pkbf(p[2 * j][nq][2],     p[2 * j][nq][3]);
                unsigned b0 = pkbf(p[2 * j + 1][nq][0], p[2 * j + 1][nq][1]);
                unsigned b1 = pkbf(p[2 * j + 1][nq][2], p[2 * j + 1][nq][3]);
                perm32(a0, b0); perm32(a1, b1);   // a=[A_lo|B_lo], b=[A_hi|B_hi]
                perm16(a0, b0); perm16(a1, b1);   // a=w0/w1, b=w2/w3
                const bf16x8 pf = __builtin_bit_cast(bf16x8, u32x4{a0, a1, b0, b1});
#pragma unroll
                for (int mtv = 0; mtv < 8; ++mtv)
                    o[mtv][nq] = __builtin_amdgcn_mfma_f32_16x16x32_bf16(vb[mtv], pf, o[mtv][nq], 0, 0, 0);
            }
        }
    }

    // final l per qrow: reduce per-lane partials across quads
#pragma unroll
    for (int nq = 0; nq < 2; ++nq) {
        float v = psum[nq];
        v += __shfl_xor(v, 16);
        v += __shfl_xor(v, 32);
        psum[nq] = v;
    }

    // epilogue: AO[qrow][h*128 + d], packed 8B stores
#pragma unroll
    for (int nq = 0; nq < 2; ++nq) {
        const float rinv = 1.0f / psum[nq];
        const size_t row = (size_t)(rowbase + wrow + nq * 16 + c) * 2048 + h * 128;
#pragma unroll
        for (int mtv = 0; mtv < 8; ++mtv) {
            bf16x4 v;
#pragma unroll
            for (int r = 0; r < 4; ++r) v[r] = (bf16)(o[mtv][nq][r] * rinv);
            *(bf16x4*)(AO + row + mtv * 16 + q * 4) = v;
        }
    }
}

// ---------------------------------------------------------------------------
extern "C" void kernel_launch(void* const* d_in, const int* in_sizes, int n_in,
                              void* d_out, int out_size, void* d_ws, size_t ws_size,
                              hipStream_t stream)
{
    const float* x  = (const float*)d_in[0];
    const float* wq = (const float*)d_in[1];
    const float* wk = (const float*)d_in[2];
    const float* wv = (const float*)d_in[3];
    const float* wo = (const float*)d_in[4];
    float* out = (float*)d_out;

    // workspace (bf16), 51 MiB total:
    // xb@0(16M) wqb@16M(8M) wkb@24M(.5M) wvb@24.5M(.5M) wob@25M(8M) Qb/AO@33M(16M) Kb@49M(1M) Vt@50M(1M)
    char* ws = (char*)d_ws;
    const size_t MB = 1024 * 1024;
    bf16* xb  = (bf16*)(ws);
    bf16* wqb = (bf16*)(ws + 16 * MB);
    bf16* wkb = (bf16*)(ws + 24 * MB);
    bf16* wvb = (bf16*)(ws + 24 * MB + 512 * 1024);
    bf16* wob = (bf16*)(ws + 25 * MB);
    bf16* Qb  = (bf16*)(ws + 33 * MB);
    bf16* AO  = Qb;                            // alias (safe, see attn note)
    bf16* Kb  = (bf16*)(ws + 49 * MB);
    bf16* Vt  = (bf16*)(ws + 50 * MB);

    cvt_all<<<17301504 / 2048, 256, 0, stream>>>(x, wq, wk, wv, wo, xb);
    qkv_kernel<<<dim3(18, 32), 256, 0, stream>>>(xb, wqb, wkb, wvb, Qb, Kb, Vt);
    attn_kernel<<<dim3(16, 16, 2), 256, 0, stream>>>(Qb, Kb, Vt, AO);
    out_kernel<<<dim3(16, 32), 256, 0, stream>>>(AO, wob, out);
}